// Round 9
// baseline (231.399 us; speedup 1.0000x reference)
//
#include <hip/hip_runtime.h>

#define BB 4
#define TT 2048
#define CC 768
#define QKVW 2304          // 3*CC
#define NHH 12
#define HSS 64
#define NQT64 (TT / 64)    // 32 q-tiles of 64

typedef __attribute__((ext_vector_type(4))) float floatx4;
typedef __attribute__((ext_vector_type(8))) short shortx8;
typedef __attribute__((ext_vector_type(4))) short shortx4;

__device__ __forceinline__ unsigned short f2bf(float f) {  // RNE
  union { float f; unsigned int u; } cv; cv.f = f;
  unsigned int u = cv.u;
  u += 0x7FFFu + ((u >> 16) & 1u);
  return (unsigned short)(u >> 16);
}
__device__ __forceinline__ unsigned short bfp(float f) {   // round-half-up (cheap)
  union { float f; unsigned int u; } cv; cv.f = f;
  return (unsigned short)((cv.u + 0x8000u) >> 16);
}
__device__ __forceinline__ unsigned short bft(float f) {   // truncate (1 op)
  union { float f; unsigned int u; } cv; cv.f = f;
  return (unsigned short)(cv.u >> 16);
}

// async global->LDS, 16B per lane; LDS dest = wave-uniform base + lane*16
__device__ __forceinline__ void async_copy16(const void* g, void* l) {
  __builtin_amdgcn_global_load_lds(
      (const __attribute__((address_space(1))) unsigned int*)g,
      (__attribute__((address_space(3))) unsigned int*)l, 16, 0, 0);
}

// ---------- prep (fused): convert_x + transpose_w(attn) + transpose_w(proj) ----
// (verified R15) blocks 0..1023 convert x->bf16; 1024..1455 transpose w_attn;
// 1456..1599 transpose w_proj.
__global__ __launch_bounds__(256)
void prep_fused(const float* __restrict__ x, unsigned short* __restrict__ xb, int n4,
                const float* __restrict__ wa, unsigned short* __restrict__ wta,
                const float* __restrict__ wp, unsigned short* __restrict__ wtp) {
  __shared__ short tile[64 * 68];
  const int bid = blockIdx.x;
  const int tid = threadIdx.x;
  if (bid < 1024) {
    int i = bid * 256 + tid;
    const int stride = 1024 * 256;
    for (; i < n4; i += stride) {
      float4 v = ((const float4*)x)[i];
      shortx4 s;
      s.x = (short)f2bf(v.x); s.y = (short)f2bf(v.y);
      s.z = (short)f2bf(v.z); s.w = (short)f2bf(v.w);
      ((shortx4*)xb)[i] = s;
    }
    return;
  }
  const float* w; unsigned short* wt; int N, n0, k0;
  if (bid < 1456) {
    const int t = bid - 1024;            // 0..431 : w_attn [768][2304]
    w = wa; wt = wta; N = QKVW; n0 = (t % 36) * 64; k0 = (t / 36) * 64;
  } else {
    const int t = bid - 1456;            // 0..143 : w_proj [768][768]
    w = wp; wt = wtp; N = CC;   n0 = (t % 12) * 64; k0 = (t / 12) * 64;
  }
  const int K = CC;
  {
    const int tr = tid >> 4, tc = (tid & 15) * 4;
#pragma unroll
    for (int i = 0; i < 4; ++i) {
      float4 v = *(const float4*)(w + (size_t)(k0 + tr + 16 * i) * N + n0 + tc);
      short* d = &tile[(tr + 16 * i) * 68 + tc];
      d[0] = (short)f2bf(v.x); d[1] = (short)f2bf(v.y);
      d[2] = (short)f2bf(v.z); d[3] = (short)f2bf(v.w);
    }
  }
  __syncthreads();
  {
    const int wr = tid >> 3, wc = (tid & 7) * 8;
#pragma unroll
    for (int j = 0; j < 2; ++j) {
      const int n = wr + 32 * j;
      shortx8 s;
#pragma unroll
      for (int e = 0; e < 8; ++e) s[e] = tile[(wc + e) * 68 + n];
      *(shortx8*)(wt + (size_t)(n0 + n) * K + k0 + wc) = s;
    }
  }
}

// V part of qkv -> Vt[bh][d][t] bf16, keyPerm within 32-blocks.
// VERIFIED R8/R9. (R15's GEMM-fused V store regressed GEMM1 by 12us via
// scattered 8B stores -> reverted to this coalesced LDS-staged version.)
__global__ __launch_bounds__(256)
void transpose_v(const unsigned short* __restrict__ qkv, unsigned short* __restrict__ Vt) {
  __shared__ short tile[64 * 72];   // [t'][d]
  const int t0 = blockIdx.x * 64;
  const int bh = blockIdx.y;
  const int b = bh / NHH, h = bh % NHH;
  const int tid = threadIdx.x;
  {
    const int tr = tid >> 3, tc = (tid & 7) * 8;
#pragma unroll
    for (int i = 0; i < 2; ++i) {
      shortx8 v = *(const shortx8*)(qkv + ((size_t)(b * TT + t0 + tr + 32 * i)) * QKVW + 2 * CC + h * HSS + tc);
      *(shortx8*)&tile[(tr + 32 * i) * 72 + tc] = v;
    }
  }
  __syncthreads();
  {
    const int dr = tid >> 3, tc = (tid & 7) * 8;
    const int base = (tc & 32) + ((tc >> 3) & 3) * 4;   // 32-block + q*4
#pragma unroll
    for (int j = 0; j < 2; ++j) {
      const int d = dr + 32 * j;
      shortx8 s;
#pragma unroll
      for (int e = 0; e < 8; ++e)
        s[e] = tile[(base + (e >> 2) * 16 + (e & 3)) * 72 + d];
      *(shortx8*)(Vt + ((size_t)bh * HSS + d) * TT + t0 + tc) = s;
    }
  }
}

// ---------- GEMM1 v4: 256x128 block / 128x64 wave tile ---------------------
// R16: the 128^2 structure is LDS-pipe-bound per block-step: MFMA 310cy vs
// LDS 375cy (32 b128 reads + 16KB staging writes at 128B/clk) -> MfmaUtil
// stuck at 22%. 128x64 wave tile: 12 b128 reads feed 32 MFMA (ratio
// 2.0->2.67); per-step MFMA 620cy > LDS 576cy -> marginally MFMA-bound.
// Same verified 3-deep counted-vmcnt skeleton, rescaled: 6 loads/wave/tile
// -> vmcnt(12)/(6)/(0); LDS 72KB (2 blocks/CU); identical both-sides XOR
// swizzle (f(row)=(row>>1)&3 is row-mod-16-consistent on both sides).
__global__ __launch_bounds__(256)
void gemm1_256(const unsigned short* __restrict__ A, const unsigned short* __restrict__ Bt,
               const float* __restrict__ bias, unsigned short* __restrict__ C,
               int M, int N, int K) {
  __shared__ short As[3][256 * 32];   // 48KB
  __shared__ short Bs[3][128 * 32];   // 24KB
  const int tid = threadIdx.x, lane = tid & 63, wave = tid >> 6;
  const int row = lane & 15, quad = lane >> 4;
  const int wm = (wave >> 1) * 128, wn = (wave & 1) * 64;
  const int m0 = blockIdx.x * 256, n0 = blockIdx.y * 128;

  floatx4 acc[8][4] = {};

  const int lr = lane >> 2;                       // local row in 16-row granule
  const int csrc = (lane & 3) ^ ((lr >> 1) & 3);  // swizzled source chunk
  const unsigned short* aP = A + (size_t)(m0 + wave * 64 + lr) * K + csrc * 8;
  const unsigned short* bP = Bt + (size_t)(n0 + wave * 32 + lr) * K + csrc * 8;
  const int aOff = (wave * 64) * 32;              // LDS bases (shorts)
  const int bOff = (wave * 32) * 32;

  // fragment read chunk (loop-invariant): quad ^ f(row)
  const int qsw = (quad ^ ((row >> 1) & 3)) * 8;

  const int nk = K >> 5;                          // 24 for K=768

  auto stage = [&](int t, int bi) {
#pragma unroll
    for (int i = 0; i < 4; ++i)
      async_copy16(aP + (size_t)(16 * i) * K + t * 32, &As[bi][aOff + i * 512]);
#pragma unroll
    for (int i = 0; i < 2; ++i)
      async_copy16(bP + (size_t)(16 * i) * K + t * 32, &Bs[bi][bOff + i * 512]);
  };

  stage(0, 0);
  stage(1, 1);
  int cb = 0;
  for (int t = 0; t < nk; ++t) {
    int pb = cb + 2; if (pb >= 3) pb -= 3;
    if (t + 2 < nk) {
      stage(t + 2, pb);
      asm volatile("s_waitcnt vmcnt(12)" ::: "memory");  // tile t landed
    } else if (t + 1 < nk) {
      asm volatile("s_waitcnt vmcnt(6)" ::: "memory");
    } else {
      asm volatile("s_waitcnt vmcnt(0)" ::: "memory");
    }
    __builtin_amdgcn_sched_barrier(0);
    __builtin_amdgcn_s_barrier();
    __builtin_amdgcn_sched_barrier(0);
    {
      shortx8 af[8], bf[4];
#pragma unroll
      for (int g = 0; g < 8; ++g)
        af[g] = *(const shortx8*)&As[cb][(wm + g * 16 + row) * 32 + qsw];
#pragma unroll
      for (int g = 0; g < 4; ++g)
        bf[g] = *(const shortx8*)&Bs[cb][(wn + g * 16 + row) * 32 + qsw];
#pragma unroll
      for (int mg = 0; mg < 8; ++mg)
#pragma unroll
        for (int ng = 0; ng < 4; ++ng)
          acc[mg][ng] = __builtin_amdgcn_mfma_f32_16x16x32_bf16(af[mg], bf[ng], acc[mg][ng], 0, 0, 0);
    }
    __builtin_amdgcn_sched_barrier(0);
    __builtin_amdgcn_s_barrier();
    __builtin_amdgcn_sched_barrier(0);
    cb = (cb + 1 == 3) ? 0 : cb + 1;
  }

#pragma unroll
  for (int mg = 0; mg < 8; ++mg) {
    const int m = m0 + wm + mg * 16 + quad * 4;
#pragma unroll
    for (int ng = 0; ng < 4; ++ng) {
      const int n = n0 + wn + ng * 16 + row;
      const float bv = bias[n];
      // fold attn 1/sqrt(HS) AND log2(e) into q (softmax uses exp2)
      const float scl = (n < CC) ? 0.180336881f : 1.0f;
#pragma unroll
      for (int r = 0; r < 4; ++r)
        C[(size_t)(m + r) * N + n] = f2bf((acc[mg][ng][r] + bv) * scl);
    }
  }
}

// ---------- GEMM v3b (128^2): frozen, used for GEMM2 (192 blocks would
// underfill 256 CUs at 256-tile) -- verified R11/R13: 0 bank conflicts.
template<bool OUT_BF16, bool QSCALE>
__global__ __launch_bounds__(256)
void gemm_tn(const unsigned short* __restrict__ A, const unsigned short* __restrict__ Bt,
             const float* __restrict__ bias, void* __restrict__ Cp, int M, int N, int K) {
  __shared__ short As[3][128 * 32];
  __shared__ short Bs[3][128 * 32];
  const int tid = threadIdx.x, lane = tid & 63, wave = tid >> 6;
  const int row = lane & 15, quad = lane >> 4;
  const int wm = (wave >> 1) * 64, wn = (wave & 1) * 64;
  const int m0 = blockIdx.x * 128, n0 = blockIdx.y * 128;

  floatx4 acc[4][4] = {};

  const int lr = lane >> 2;                       // local row in 16-row granule
  const int csrc = (lane & 3) ^ ((lr >> 1) & 3);  // swizzled source chunk
  const int sr = wave * 32 + lr;
  const unsigned short* aP = A + (size_t)(m0 + sr) * K + csrc * 8;
  const unsigned short* bP = Bt + (size_t)(n0 + sr) * K + csrc * 8;
  const int sOff = (wave * 32) * 32;              // this wave's LDS base (shorts)

  const int qsw = (quad ^ ((row >> 1) & 3)) * 8;

  const int nk = K >> 5;                          // BK=32 steps (24 for K=768)

  auto stage = [&](int t, int bi) {
#pragma unroll
    for (int i = 0; i < 2; ++i) {
      async_copy16(aP + (size_t)(16 * i) * K + t * 32, &As[bi][sOff + i * 512]);
      async_copy16(bP + (size_t)(16 * i) * K + t * 32, &Bs[bi][sOff + i * 512]);
    }
  };

  stage(0, 0);
  if (nk > 1) stage(1, 1);
  int cb = 0;
  for (int t = 0; t < nk; ++t) {
    int pb = cb + 2; if (pb >= 3) pb -= 3;
    if (t + 2 < nk) {
      stage(t + 2, pb);
      asm volatile("s_waitcnt vmcnt(8)" ::: "memory");   // tile t landed
    } else if (t + 1 < nk) {
      asm volatile("s_waitcnt vmcnt(4)" ::: "memory");
    } else {
      asm volatile("s_waitcnt vmcnt(0)" ::: "memory");
    }
    __builtin_amdgcn_sched_barrier(0);
    __builtin_amdgcn_s_barrier();
    __builtin_amdgcn_sched_barrier(0);
    {
      shortx8 af[4], bf[4];
#pragma unroll
      for (int g = 0; g < 4; ++g) {
        af[g] = *(const shortx8*)&As[cb][(wm + g * 16 + row) * 32 + qsw];
        bf[g] = *(const shortx8*)&Bs[cb][(wn + g * 16 + row) * 32 + qsw];
      }
#pragma unroll
      for (int mg = 0; mg < 4; ++mg)
#pragma unroll
        for (int ng = 0; ng < 4; ++ng)
          acc[mg][ng] = __builtin_amdgcn_mfma_f32_16x16x32_bf16(af[mg], bf[ng], acc[mg][ng], 0, 0, 0);
    }
    __builtin_amdgcn_sched_barrier(0);
    __builtin_amdgcn_s_barrier();
    __builtin_amdgcn_sched_barrier(0);
    cb = (cb + 1 == 3) ? 0 : cb + 1;
  }

#pragma unroll
  for (int mg = 0; mg < 4; ++mg) {
    const int m = m0 + wm + mg * 16 + quad * 4;
#pragma unroll
    for (int ng = 0; ng < 4; ++ng) {
      const int n = n0 + wn + ng * 16 + row;
      const float bv = bias[n];
      const float scl = (QSCALE && n < CC) ? 0.180336881f : 1.0f;
#pragma unroll
      for (int r = 0; r < 4; ++r) {
        const float val = (acc[mg][ng][r] + bv) * scl;
        if (OUT_BF16) ((unsigned short*)Cp)[(size_t)(m + r) * N + n] = f2bf(val);
        else          ((float*)Cp)[(size_t)(m + r) * N + n] = val;
      }
    }
  }
}

// ---------- flash attention v12: gemm-v3b-style DMA pipeline for K/V -------
// (frozen from R14 — verified)
__global__ __launch_bounds__(256)
void attn_kernel(const unsigned short* __restrict__ qkv, const unsigned short* __restrict__ Vt,
                 unsigned short* __restrict__ y) {
  __shared__ short Ksh[3][64 * 64];   // [key][d], chunk-XOR swizzled
  __shared__ short Vsh[3][64 * 64];   // [d][keyPerm], chunk-XOR swizzled

  // XCD-locality + LPT decode (assumes round-robin blockIdx%8 -> XCD)
  const int id = blockIdx.x;          // 0..1535
  const int xcd = id & 7;
  const int slot = id >> 3;           // 0..191
  const int qt = NQT64 - 1 - slot / 6;   // 31..0, heavy first
  const int gl = slot % 6;
  const int g = xcd * 6 + gl;         // 0..47 = (b,h) group
  const int h = g % NHH, b = g / NHH;
  const int bh = b * NHH + h;
  const int tid = threadIdx.x, lane = tid & 63, wave = tid >> 6;
  const int row = lane & 15, quad = lane >> 4;
  const int qhalf = wave & 1;         // which 32 queries of the 64-q item
  const int khalf = wave >> 1;        // which 32 keys of each 64-key tile

  const unsigned short* kSrc = qkv + ((size_t)(b * TT)) * QKVW + CC + h * HSS;
  const unsigned short* vSrc = Vt + ((size_t)bh * HSS) * TT;

  const shortx8 ones8 = {(short)0x3F80, (short)0x3F80, (short)0x3F80, (short)0x3F80,
                         (short)0x3F80, (short)0x3F80, (short)0x3F80, (short)0x3F80};

  const int qb0 = qt * 64 + qhalf * 32;             // wave's 32 queries
  const int nk = qt + 1;

  // ---- staging source per-lane offsets (inverse-swizzled chunk) ----
  const int lr8 = lane >> 3;          // 0..7 (== staged row & 7)
  const int csw = ((lane & 7) ^ lr8) * 8;
  size_t kOff[2], vOff[2];
#pragma unroll
  for (int i = 0; i < 2; ++i) {
    const int r = wave * 16 + i * 8 + lr8;
    kOff[i] = (size_t)r * QKVW + csw;
    vOff[i] = (size_t)r * TT + csw;
  }
  const int sBase = (wave * 16) * 64; // this wave's LDS base (shorts), +i*512

  // ---- read offsets (loop-invariant, chunk-XOR by row&7) ----
  const int r7 = row & 7;
  int kR[2][2], vR[4];
#pragma unroll
  for (int mg = 0; mg < 2; ++mg) {
    const int krow = khalf * 32 + mg * 16 + row;
    kR[mg][0] = krow * 64 + ((quad ^ r7) * 8);
    kR[mg][1] = krow * 64 + (((quad + 4) ^ r7) * 8);
  }
#pragma unroll
  for (int dg = 0; dg < 4; ++dg)
    vR[dg] = (dg * 16 + row) * 64 + (((khalf * 4 + quad) ^ r7) * 8);

  // Q fragments (B-operand of S^T MFMA); pre-scaled by 0.125*log2e in GEMM1
  shortx8 qf[2][2];
#pragma unroll
  for (int qg = 0; qg < 2; ++qg) {
    const unsigned short* qp = qkv + ((size_t)(b * TT) + qb0 + qg * 16 + row) * QKVW + h * HSS;
    qf[qg][0] = *(const shortx8*)(qp + quad * 8);
    qf[qg][1] = *(const shortx8*)(qp + 32 + quad * 8);
  }
  asm volatile("s_waitcnt vmcnt(0)" ::: "memory");   // Q done -> exact DMA counting

  floatx4 lf[2] = {(floatx4)(0.0f), (floatx4)(0.0f)};  // partial l (this khalf)
  floatx4 o[2][4];                  // [qg][dg]: O[q=quad*4+r][d=dg*16+row] partial
#pragma unroll
  for (int qg = 0; qg < 2; ++qg)
#pragma unroll
    for (int dg = 0; dg < 4; ++dg) o[qg][dg] = (floatx4)(0.0f);

  auto stage = [&](int t, int bi) {
#pragma unroll
    for (int i = 0; i < 2; ++i) {
      async_copy16(kSrc + (size_t)(t * 64) * QKVW + kOff[i], &Ksh[bi][sBase + i * 512]);
      async_copy16(vSrc + (size_t)(t * 64) + vOff[i],        &Vsh[bi][sBase + i * 512]);
    }
  };

  stage(0, 0);
  if (nk > 1) stage(1, 1);
  int cb = 0;
  for (int kt = 0; kt < nk; ++kt) {
    int pb = cb + 2; if (pb >= 3) pb -= 3;
    if (kt + 2 < nk) {
      stage(kt + 2, pb);
      asm volatile("s_waitcnt vmcnt(8)" ::: "memory");   // tile kt landed
    } else if (kt + 1 < nk) {
      asm volatile("s_waitcnt vmcnt(4)" ::: "memory");
    } else {
      asm volatile("s_waitcnt vmcnt(0)" ::: "memory");
    }
    __builtin_amdgcn_sched_barrier(0);
    __builtin_amdgcn_s_barrier();
    __builtin_amdgcn_sched_barrier(0);
    {
      const short* Kc = &Ksh[cb][0];
      const short* Vc = &Vsh[cb][0];
      __builtin_amdgcn_s_setprio(1);
      // ---- S^T = K @ Q^T (this wave: 32 keys x 32 queries) ----
      shortx4 pfr[2][2];
#pragma unroll
      for (int mg = 0; mg < 2; ++mg) {
        const shortx8 kf0 = *(const shortx8*)&Kc[kR[mg][0]];
        const shortx8 kf1 = *(const shortx8*)&Kc[kR[mg][1]];
#pragma unroll
        for (int qg = 0; qg < 2; ++qg) {
          floatx4 t = __builtin_amdgcn_mfma_f32_16x16x32_bf16(kf0, qf[qg][0], (floatx4)(0.0f), 0, 0, 0);
          t = __builtin_amdgcn_mfma_f32_16x16x32_bf16(kf1, qf[qg][1], t, 0, 0, 0);
          if (kt == qt) {  // diagonal tile: causal mask (key > query)
            const int kg = kt * 64 + khalf * 32 + mg * 16 + quad * 4;
            const int qv = qb0 + qg * 16 + row;
#pragma unroll
            for (int r = 0; r < 4; ++r)
              if (kg + r > qv) t[r] = -1e30f;
          }
          // softmax numerator: p = exp2(s), fixed max, truncation pack
          shortx4 pk;
#pragma unroll
          for (int r = 0; r < 4; ++r) pk[r] = (short)bft(__builtin_amdgcn_exp2f(t[r]));
          pfr[qg][mg] = pk;
        }
      }
      // ---- O += P @ V ; l += P @ 1 — k=32 MFMA over this wave's 32 keys ----
      shortx8 pk8[2];
#pragma unroll
      for (int qg = 0; qg < 2; ++qg) {
        pk8[qg] = __builtin_shufflevector(pfr[qg][0], pfr[qg][1], 0, 1, 2, 3, 4, 5, 6, 7);
        lf[qg] = __builtin_amdgcn_mfma_f32_16x16x32_bf16(pk8[qg], ones8, lf[qg], 0, 0, 0);
      }
#pragma unroll
      for (int dg = 0; dg < 4; ++dg) {
        const shortx8 vf = *(const shortx8*)&Vc[vR[dg]];
#pragma unroll
        for (int qg = 0; qg < 2; ++qg)
          o[qg][dg] = __builtin_amdgcn_mfma_f32_16x16x32_bf16(pk8[qg], vf, o[qg][dg], 0, 0, 0);
      }
      __builtin_amdgcn_s_setprio(0);
    }
    __builtin_amdgcn_sched_barrier(0);
    __builtin_amdgcn_s_barrier();
    __builtin_amdgcn_sched_barrier(0);
    cb = (cb + 1 == 3) ? 0 : cb + 1;
  }

  // ---- cross-khalf reduction of O,l through (dead) Ksh region ----
  floatx4* red4 = (floatx4*)(&Ksh[0][0]);   // 2*64*11*16B = 22.5KB <= 24KB
  const int rbase = (qhalf * 64 + lane) * 11;
  if (khalf) {
#pragma unroll
    for (int qg = 0; qg < 2; ++qg) {
#pragma unroll
      for (int dg = 0; dg < 4; ++dg) red4[rbase + qg * 4 + dg] = o[qg][dg];
      red4[rbase + 8 + qg] = lf[qg];
    }
  }
  __syncthreads();
  if (!khalf) {
#pragma unroll
    for (int qg = 0; qg < 2; ++qg) {
#pragma unroll
      for (int dg = 0; dg < 4; ++dg) o[qg][dg] += red4[rbase + qg * 4 + dg];
      lf[qg] += red4[rbase + 8 + qg];
    }
    // epilogue: l is per-lane in C-layout -> no shuffles at all
#pragma unroll
    for (int qg = 0; qg < 2; ++qg) {
#pragma unroll
      for (int r = 0; r < 4; ++r) {
        const float lo = 1.0f / lf[qg][r];
        unsigned short* yp = y + ((size_t)(b * TT) + qb0 + qg * 16 + quad * 4 + r) * CC + h * HSS;
#pragma unroll
        for (int dg = 0; dg < 4; ++dg)
          yp[dg * 16 + row] = bfp(o[qg][dg][r] * lo);
      }
    }
  }
}

extern "C" void kernel_launch(void* const* d_in, const int* in_sizes, int n_in,
                              void* d_out, int out_size, void* d_ws, size_t ws_size,
                              hipStream_t stream) {
  const float* x      = (const float*)d_in[0];
  const float* w_attn = (const float*)d_in[1];
  const float* b_attn = (const float*)d_in[2];
  const float* w_proj = (const float*)d_in[3];
  const float* b_proj = (const float*)d_in[4];
  float* out = (float*)d_out;

  char* ws = (char*)d_ws;
  unsigned short* xb  = (unsigned short*)ws;
  unsigned short* y   = (unsigned short*)ws;                          // reuse after GEMM1
  unsigned short* qkv = (unsigned short*)(ws + 12582912);
  unsigned short* wta = (unsigned short*)(ws + 50331648);
  unsigned short* Vt  = (unsigned short*)(ws + 50331648);             // overlays wta post-GEMM1
  unsigned short* wtp = (unsigned short*)(ws + 62914560);

  const int M = BB * TT;  // 8192

  prep_fused<<<1600, 256, 0, stream>>>(x, xb, (M * CC) / 4, w_attn, wta, w_proj, wtp);

  gemm1_256<<<dim3(M / 256, QKVW / 128), 256, 0, stream>>>(
      xb, wta, b_attn, qkv, M, QKVW, CC);

  transpose_v<<<dim3(TT / 64, BB * NHH), 256, 0, stream>>>(qkv, Vt);

  attn_kernel<<<dim3(NQT64 * NHH * BB), 256, 0, stream>>>(qkv, Vt, y);

  gemm_tn<false, false><<<dim3(M / 128, CC / 128), 256, 0, stream>>>(
      y, wtp, b_proj, (void*)out, M, CC, CC);
}

// Round 10
// 196.380 us; speedup vs baseline: 1.1783x; 1.1783x over previous
//
#include <hip/hip_runtime.h>

#define BB 4
#define TT 2048
#define CC 768
#define QKVW 2304          // 3*CC
#define NHH 12
#define HSS 64
#define NQT64 (TT / 64)    // 32 q-tiles of 64

typedef __attribute__((ext_vector_type(4))) float floatx4;
typedef __attribute__((ext_vector_type(8))) short shortx8;
typedef __attribute__((ext_vector_type(4))) short shortx4;

__device__ __forceinline__ unsigned short f2bf(float f) {  // RNE
  union { float f; unsigned int u; } cv; cv.f = f;
  unsigned int u = cv.u;
  u += 0x7FFFu + ((u >> 16) & 1u);
  return (unsigned short)(u >> 16);
}
__device__ __forceinline__ unsigned short bfp(float f) {   // round-half-up (cheap)
  union { float f; unsigned int u; } cv; cv.f = f;
  return (unsigned short)((cv.u + 0x8000u) >> 16);
}
__device__ __forceinline__ unsigned short bft(float f) {   // truncate (1 op)
  union { float f; unsigned int u; } cv; cv.f = f;
  return (unsigned short)(cv.u >> 16);
}

// async global->LDS, 16B per lane; LDS dest = wave-uniform base + lane*16
__device__ __forceinline__ void async_copy16(const void* g, void* l) {
  __builtin_amdgcn_global_load_lds(
      (const __attribute__((address_space(1))) unsigned int*)g,
      (__attribute__((address_space(3))) unsigned int*)l, 16, 0, 0);
}

// ---------- prep (fused): convert_x + transpose_w(attn) + transpose_w(proj) ----
// (verified R15; saved ~12us vs 3 separate launches) blocks 0..1023 convert
// x->bf16; 1024..1455 transpose w_attn; 1456..1599 transpose w_proj.
__global__ __launch_bounds__(256)
void prep_fused(const float* __restrict__ x, unsigned short* __restrict__ xb, int n4,
                const float* __restrict__ wa, unsigned short* __restrict__ wta,
                const float* __restrict__ wp, unsigned short* __restrict__ wtp) {
  __shared__ short tile[64 * 68];
  const int bid = blockIdx.x;
  const int tid = threadIdx.x;
  if (bid < 1024) {
    int i = bid * 256 + tid;
    const int stride = 1024 * 256;
    for (; i < n4; i += stride) {
      float4 v = ((const float4*)x)[i];
      shortx4 s;
      s.x = (short)f2bf(v.x); s.y = (short)f2bf(v.y);
      s.z = (short)f2bf(v.z); s.w = (short)f2bf(v.w);
      ((shortx4*)xb)[i] = s;
    }
    return;
  }
  const float* w; unsigned short* wt; int N, n0, k0;
  if (bid < 1456) {
    const int t = bid - 1024;            // 0..431 : w_attn [768][2304]
    w = wa; wt = wta; N = QKVW; n0 = (t % 36) * 64; k0 = (t / 36) * 64;
  } else {
    const int t = bid - 1456;            // 0..143 : w_proj [768][768]
    w = wp; wt = wtp; N = CC;   n0 = (t % 12) * 64; k0 = (t / 12) * 64;
  }
  const int K = CC;
  {
    const int tr = tid >> 4, tc = (tid & 15) * 4;
#pragma unroll
    for (int i = 0; i < 4; ++i) {
      float4 v = *(const float4*)(w + (size_t)(k0 + tr + 16 * i) * N + n0 + tc);
      short* d = &tile[(tr + 16 * i) * 68 + tc];
      d[0] = (short)f2bf(v.x); d[1] = (short)f2bf(v.y);
      d[2] = (short)f2bf(v.z); d[3] = (short)f2bf(v.w);
    }
  }
  __syncthreads();
  {
    const int wr = tid >> 3, wc = (tid & 7) * 8;
#pragma unroll
    for (int j = 0; j < 2; ++j) {
      const int n = wr + 32 * j;
      shortx8 s;
#pragma unroll
      for (int e = 0; e < 8; ++e) s[e] = tile[(wc + e) * 68 + n];
      *(shortx8*)(wt + (size_t)(n0 + n) * K + k0 + wc) = s;
    }
  }
}

// V part of qkv -> Vt[bh][d][t] bf16, keyPerm within 32-blocks.
// VERIFIED R8/R9. (R15's GEMM-fused V store regressed GEMM1 by 12us via
// scattered 8B stores; R16's 256-tile GEMM1 regressed via occupancy ->
// both reverted. This coalesced LDS-staged transpose stays.)
__global__ __launch_bounds__(256)
void transpose_v(const unsigned short* __restrict__ qkv, unsigned short* __restrict__ Vt) {
  __shared__ short tile[64 * 72];   // [t'][d]
  const int t0 = blockIdx.x * 64;
  const int bh = blockIdx.y;
  const int b = bh / NHH, h = bh % NHH;
  const int tid = threadIdx.x;
  {
    const int tr = tid >> 3, tc = (tid & 7) * 8;
#pragma unroll
    for (int i = 0; i < 2; ++i) {
      shortx8 v = *(const shortx8*)(qkv + ((size_t)(b * TT + t0 + tr + 32 * i)) * QKVW + 2 * CC + h * HSS + tc);
      *(shortx8*)&tile[(tr + 32 * i) * 72 + tc] = v;
    }
  }
  __syncthreads();
  {
    const int dr = tid >> 3, tc = (tid & 7) * 8;
    const int base = (tc & 32) + ((tc >> 3) & 3) * 4;   // 32-block + q*4
#pragma unroll
    for (int j = 0; j < 2; ++j) {
      const int d = dr + 32 * j;
      shortx8 s;
#pragma unroll
      for (int e = 0; e < 8; ++e)
        s[e] = tile[(base + (e >> 2) * 16 + (e & 3)) * 72 + d];
      *(shortx8*)(Vt + ((size_t)bh * HSS + d) * TT + t0 + tc) = s;
    }
  }
}

// ---------- GEMM v3b (128^2): 3-deep pipelined BK=32, counted vmcnt --------
// FROZEN. Verified R11/R13: GEMM1 50.5us / 574 TF, 0 bank conflicts,
// 3 blocks/CU. R16's 256x128 variant (2 blocks/CU, grid 2.25/CU) regressed
// to 83us — occupancy floor rule: never drop below 3 resident blocks/CU.
template<bool OUT_BF16, bool QSCALE>
__global__ __launch_bounds__(256)
void gemm_tn(const unsigned short* __restrict__ A, const unsigned short* __restrict__ Bt,
             const float* __restrict__ bias, void* __restrict__ Cp, int M, int N, int K) {
  __shared__ short As[3][128 * 32];
  __shared__ short Bs[3][128 * 32];
  const int tid = threadIdx.x, lane = tid & 63, wave = tid >> 6;
  const int row = lane & 15, quad = lane >> 4;
  const int wm = (wave >> 1) * 64, wn = (wave & 1) * 64;
  const int m0 = blockIdx.x * 128, n0 = blockIdx.y * 128;

  floatx4 acc[4][4] = {};

  const int lr = lane >> 2;                       // local row in 16-row granule
  const int csrc = (lane & 3) ^ ((lr >> 1) & 3);  // swizzled source chunk
  const int sr = wave * 32 + lr;
  const unsigned short* aP = A + (size_t)(m0 + sr) * K + csrc * 8;
  const unsigned short* bP = Bt + (size_t)(n0 + sr) * K + csrc * 8;
  const int sOff = (wave * 32) * 32;              // this wave's LDS base (shorts)

  const int qsw = (quad ^ ((row >> 1) & 3)) * 8;

  const int nk = K >> 5;                          // BK=32 steps (24 for K=768)

  auto stage = [&](int t, int bi) {
#pragma unroll
    for (int i = 0; i < 2; ++i) {
      async_copy16(aP + (size_t)(16 * i) * K + t * 32, &As[bi][sOff + i * 512]);
      async_copy16(bP + (size_t)(16 * i) * K + t * 32, &Bs[bi][sOff + i * 512]);
    }
  };

  stage(0, 0);
  if (nk > 1) stage(1, 1);
  int cb = 0;
  for (int t = 0; t < nk; ++t) {
    int pb = cb + 2; if (pb >= 3) pb -= 3;
    if (t + 2 < nk) {
      stage(t + 2, pb);
      asm volatile("s_waitcnt vmcnt(8)" ::: "memory");   // tile t landed
    } else if (t + 1 < nk) {
      asm volatile("s_waitcnt vmcnt(4)" ::: "memory");
    } else {
      asm volatile("s_waitcnt vmcnt(0)" ::: "memory");
    }
    __builtin_amdgcn_sched_barrier(0);
    __builtin_amdgcn_s_barrier();
    __builtin_amdgcn_sched_barrier(0);
    {
      shortx8 af[4], bf[4];
#pragma unroll
      for (int g = 0; g < 4; ++g) {
        af[g] = *(const shortx8*)&As[cb][(wm + g * 16 + row) * 32 + qsw];
        bf[g] = *(const shortx8*)&Bs[cb][(wn + g * 16 + row) * 32 + qsw];
      }
#pragma unroll
      for (int mg = 0; mg < 4; ++mg)
#pragma unroll
        for (int ng = 0; ng < 4; ++ng)
          acc[mg][ng] = __builtin_amdgcn_mfma_f32_16x16x32_bf16(af[mg], bf[ng], acc[mg][ng], 0, 0, 0);
    }
    __builtin_amdgcn_sched_barrier(0);
    __builtin_amdgcn_s_barrier();
    __builtin_amdgcn_sched_barrier(0);
    cb = (cb + 1 == 3) ? 0 : cb + 1;
  }

#pragma unroll
  for (int mg = 0; mg < 4; ++mg) {
    const int m = m0 + wm + mg * 16 + quad * 4;
#pragma unroll
    for (int ng = 0; ng < 4; ++ng) {
      const int n = n0 + wn + ng * 16 + row;
      const float bv = bias[n];
      // fold attn 1/sqrt(HS) AND log2(e) into q (softmax uses exp2)
      const float scl = (QSCALE && n < CC) ? 0.180336881f : 1.0f;
#pragma unroll
      for (int r = 0; r < 4; ++r) {
        const float val = (acc[mg][ng][r] + bv) * scl;
        if (OUT_BF16) ((unsigned short*)Cp)[(size_t)(m + r) * N + n] = f2bf(val);
        else          ((float*)Cp)[(size_t)(m + r) * N + n] = val;
      }
    }
  }
}

// ---------- flash attention v12: gemm-v3b-style DMA pipeline for K/V -------
// FROZEN (verified R14/R15). Triple-buffered K/V via global_load_lds,
// counted vmcnt(8), both-sides chunk-XOR swizzle, setprio around compute,
// XCD-pinned LPT grid (1536 blocks, 4/CU resident).
__global__ __launch_bounds__(256)
void attn_kernel(const unsigned short* __restrict__ qkv, const unsigned short* __restrict__ Vt,
                 unsigned short* __restrict__ y) {
  __shared__ short Ksh[3][64 * 64];   // [key][d], chunk-XOR swizzled
  __shared__ short Vsh[3][64 * 64];   // [d][keyPerm], chunk-XOR swizzled

  // XCD-locality + LPT decode (assumes round-robin blockIdx%8 -> XCD)
  const int id = blockIdx.x;          // 0..1535
  const int xcd = id & 7;
  const int slot = id >> 3;           // 0..191
  const int qt = NQT64 - 1 - slot / 6;   // 31..0, heavy first
  const int gl = slot % 6;
  const int g = xcd * 6 + gl;         // 0..47 = (b,h) group
  const int h = g % NHH, b = g / NHH;
  const int bh = b * NHH + h;
  const int tid = threadIdx.x, lane = tid & 63, wave = tid >> 6;
  const int row = lane & 15, quad = lane >> 4;
  const int qhalf = wave & 1;         // which 32 queries of the 64-q item
  const int khalf = wave >> 1;        // which 32 keys of each 64-key tile

  const unsigned short* kSrc = qkv + ((size_t)(b * TT)) * QKVW + CC + h * HSS;
  const unsigned short* vSrc = Vt + ((size_t)bh * HSS) * TT;

  const shortx8 ones8 = {(short)0x3F80, (short)0x3F80, (short)0x3F80, (short)0x3F80,
                         (short)0x3F80, (short)0x3F80, (short)0x3F80, (short)0x3F80};

  const int qb0 = qt * 64 + qhalf * 32;             // wave's 32 queries
  const int nk = qt + 1;

  // ---- staging source per-lane offsets (inverse-swizzled chunk) ----
  const int lr8 = lane >> 3;          // 0..7 (== staged row & 7)
  const int csw = ((lane & 7) ^ lr8) * 8;
  size_t kOff[2], vOff[2];
#pragma unroll
  for (int i = 0; i < 2; ++i) {
    const int r = wave * 16 + i * 8 + lr8;
    kOff[i] = (size_t)r * QKVW + csw;
    vOff[i] = (size_t)r * TT + csw;
  }
  const int sBase = (wave * 16) * 64; // this wave's LDS base (shorts), +i*512

  // ---- read offsets (loop-invariant, chunk-XOR by row&7) ----
  const int r7 = row & 7;
  int kR[2][2], vR[4];
#pragma unroll
  for (int mg = 0; mg < 2; ++mg) {
    const int krow = khalf * 32 + mg * 16 + row;
    kR[mg][0] = krow * 64 + ((quad ^ r7) * 8);
    kR[mg][1] = krow * 64 + (((quad + 4) ^ r7) * 8);
  }
#pragma unroll
  for (int dg = 0; dg < 4; ++dg)
    vR[dg] = (dg * 16 + row) * 64 + (((khalf * 4 + quad) ^ r7) * 8);

  // Q fragments (B-operand of S^T MFMA); pre-scaled by 0.125*log2e in GEMM1
  shortx8 qf[2][2];
#pragma unroll
  for (int qg = 0; qg < 2; ++qg) {
    const unsigned short* qp = qkv + ((size_t)(b * TT) + qb0 + qg * 16 + row) * QKVW + h * HSS;
    qf[qg][0] = *(const shortx8*)(qp + quad * 8);
    qf[qg][1] = *(const shortx8*)(qp + 32 + quad * 8);
  }
  asm volatile("s_waitcnt vmcnt(0)" ::: "memory");   // Q done -> exact DMA counting

  floatx4 lf[2] = {(floatx4)(0.0f), (floatx4)(0.0f)};  // partial l (this khalf)
  floatx4 o[2][4];                  // [qg][dg]: O[q=quad*4+r][d=dg*16+row] partial
#pragma unroll
  for (int qg = 0; qg < 2; ++qg)
#pragma unroll
    for (int dg = 0; dg < 4; ++dg) o[qg][dg] = (floatx4)(0.0f);

  auto stage = [&](int t, int bi) {
#pragma unroll
    for (int i = 0; i < 2; ++i) {
      async_copy16(kSrc + (size_t)(t * 64) * QKVW + kOff[i], &Ksh[bi][sBase + i * 512]);
      async_copy16(vSrc + (size_t)(t * 64) + vOff[i],        &Vsh[bi][sBase + i * 512]);
    }
  };

  stage(0, 0);
  if (nk > 1) stage(1, 1);
  int cb = 0;
  for (int kt = 0; kt < nk; ++kt) {
    int pb = cb + 2; if (pb >= 3) pb -= 3;
    if (kt + 2 < nk) {
      stage(kt + 2, pb);
      asm volatile("s_waitcnt vmcnt(8)" ::: "memory");   // tile kt landed
    } else if (kt + 1 < nk) {
      asm volatile("s_waitcnt vmcnt(4)" ::: "memory");
    } else {
      asm volatile("s_waitcnt vmcnt(0)" ::: "memory");
    }
    __builtin_amdgcn_sched_barrier(0);
    __builtin_amdgcn_s_barrier();
    __builtin_amdgcn_sched_barrier(0);
    {
      const short* Kc = &Ksh[cb][0];
      const short* Vc = &Vsh[cb][0];
      __builtin_amdgcn_s_setprio(1);
      // ---- S^T = K @ Q^T (this wave: 32 keys x 32 queries) ----
      shortx4 pfr[2][2];
#pragma unroll
      for (int mg = 0; mg < 2; ++mg) {
        const shortx8 kf0 = *(const shortx8*)&Kc[kR[mg][0]];
        const shortx8 kf1 = *(const shortx8*)&Kc[kR[mg][1]];
#pragma unroll
        for (int qg = 0; qg < 2; ++qg) {
          floatx4 t = __builtin_amdgcn_mfma_f32_16x16x32_bf16(kf0, qf[qg][0], (floatx4)(0.0f), 0, 0, 0);
          t = __builtin_amdgcn_mfma_f32_16x16x32_bf16(kf1, qf[qg][1], t, 0, 0, 0);
          if (kt == qt) {  // diagonal tile: causal mask (key > query)
            const int kg = kt * 64 + khalf * 32 + mg * 16 + quad * 4;
            const int qv = qb0 + qg * 16 + row;
#pragma unroll
            for (int r = 0; r < 4; ++r)
              if (kg + r > qv) t[r] = -1e30f;
          }
          // softmax numerator: p = exp2(s), fixed max, truncation pack
          shortx4 pk;
#pragma unroll
          for (int r = 0; r < 4; ++r) pk[r] = (short)bft(__builtin_amdgcn_exp2f(t[r]));
          pfr[qg][mg] = pk;
        }
      }
      // ---- O += P @ V ; l += P @ 1 — k=32 MFMA over this wave's 32 keys ----
      shortx8 pk8[2];
#pragma unroll
      for (int qg = 0; qg < 2; ++qg) {
        pk8[qg] = __builtin_shufflevector(pfr[qg][0], pfr[qg][1], 0, 1, 2, 3, 4, 5, 6, 7);
        lf[qg] = __builtin_amdgcn_mfma_f32_16x16x32_bf16(pk8[qg], ones8, lf[qg], 0, 0, 0);
      }
#pragma unroll
      for (int dg = 0; dg < 4; ++dg) {
        const shortx8 vf = *(const shortx8*)&Vc[vR[dg]];
#pragma unroll
        for (int qg = 0; qg < 2; ++qg)
          o[qg][dg] = __builtin_amdgcn_mfma_f32_16x16x32_bf16(pk8[qg], vf, o[qg][dg], 0, 0, 0);
      }
      __builtin_amdgcn_s_setprio(0);
    }
    __builtin_amdgcn_sched_barrier(0);
    __builtin_amdgcn_s_barrier();
    __builtin_amdgcn_sched_barrier(0);
    cb = (cb + 1 == 3) ? 0 : cb + 1;
  }

  // ---- cross-khalf reduction of O,l through (dead) Ksh region ----
  floatx4* red4 = (floatx4*)(&Ksh[0][0]);   // 2*64*11*16B = 22.5KB <= 24KB
  const int rbase = (qhalf * 64 + lane) * 11;
  if (khalf) {
#pragma unroll
    for (int qg = 0; qg < 2; ++qg) {
#pragma unroll
      for (int dg = 0; dg < 4; ++dg) red4[rbase + qg * 4 + dg] = o[qg][dg];
      red4[rbase + 8 + qg] = lf[qg];
    }
  }
  __syncthreads();
  if (!khalf) {
#pragma unroll
    for (int qg = 0; qg < 2; ++qg) {
#pragma unroll
      for (int dg = 0; dg < 4; ++dg) o[qg][dg] += red4[rbase + qg * 4 + dg];
      lf[qg] += red4[rbase + 8 + qg];
    }
    // epilogue: l is per-lane in C-layout -> no shuffles at all
#pragma unroll
    for (int qg = 0; qg < 2; ++qg) {
#pragma unroll
      for (int r = 0; r < 4; ++r) {
        const float lo = 1.0f / lf[qg][r];
        unsigned short* yp = y + ((size_t)(b * TT) + qb0 + qg * 16 + quad * 4 + r) * CC + h * HSS;
#pragma unroll
        for (int dg = 0; dg < 4; ++dg)
          yp[dg * 16 + row] = bfp(o[qg][dg][r] * lo);
      }
    }
  }
}

extern "C" void kernel_launch(void* const* d_in, const int* in_sizes, int n_in,
                              void* d_out, int out_size, void* d_ws, size_t ws_size,
                              hipStream_t stream) {
  const float* x      = (const float*)d_in[0];
  const float* w_attn = (const float*)d_in[1];
  const float* b_attn = (const float*)d_in[2];
  const float* w_proj = (const float*)d_in[3];
  const float* b_proj = (const float*)d_in[4];
  float* out = (float*)d_out;

  char* ws = (char*)d_ws;
  unsigned short* xb  = (unsigned short*)ws;
  unsigned short* y   = (unsigned short*)ws;                          // reuse after GEMM1
  unsigned short* qkv = (unsigned short*)(ws + 12582912);
  unsigned short* wta = (unsigned short*)(ws + 50331648);
  unsigned short* Vt  = (unsigned short*)(ws + 50331648);             // overlays wta post-GEMM1
  unsigned short* wtp = (unsigned short*)(ws + 62914560);

  const int M = BB * TT;  // 8192

  prep_fused<<<1600, 256, 0, stream>>>(x, xb, (M * CC) / 4, w_attn, wta, w_proj, wtp);

  gemm_tn<true, true><<<dim3(M / 128, QKVW / 128), 256, 0, stream>>>(
      xb, wta, b_attn, (void*)qkv, M, QKVW, CC);

  transpose_v<<<dim3(TT / 64, BB * NHH), 256, 0, stream>>>(qkv, Vt);

  attn_kernel<<<dim3(NQT64 * NHH * BB), 256, 0, stream>>>(qkv, Vt, y);

  gemm_tn<false, false><<<dim3(M / 128, CC / 128), 256, 0, stream>>>(
      y, wtp, b_proj, (void*)out, M, CC, CC);
}

// Round 11
// 195.246 us; speedup vs baseline: 1.1852x; 1.0058x over previous
//
#include <hip/hip_runtime.h>

#define BB 4
#define TT 2048
#define CC 768
#define QKVW 2304          // 3*CC
#define NHH 12
#define HSS 64
#define NQT64 (TT / 64)    // 32 q-tiles of 64

typedef __attribute__((ext_vector_type(4))) float floatx4;
typedef __attribute__((ext_vector_type(8))) short shortx8;
typedef __attribute__((ext_vector_type(4))) short shortx4;

__device__ __forceinline__ unsigned short f2bf(float f) {  // RNE
  union { float f; unsigned int u; } cv; cv.f = f;
  unsigned int u = cv.u;
  u += 0x7FFFu + ((u >> 16) & 1u);
  return (unsigned short)(u >> 16);
}
__device__ __forceinline__ unsigned short bfp(float f) {   // round-half-up (cheap)
  union { float f; unsigned int u; } cv; cv.f = f;
  return (unsigned short)((cv.u + 0x8000u) >> 16);
}
__device__ __forceinline__ unsigned short bft(float f) {   // truncate (1 op)
  union { float f; unsigned int u; } cv; cv.f = f;
  return (unsigned short)(cv.u >> 16);
}

// async global->LDS, 16B per lane; LDS dest = wave-uniform base + lane*16
__device__ __forceinline__ void async_copy16(const void* g, void* l) {
  __builtin_amdgcn_global_load_lds(
      (const __attribute__((address_space(1))) unsigned int*)g,
      (__attribute__((address_space(3))) unsigned int*)l, 16, 0, 0);
}

// ---------- prep (fused): convert_x + transpose_w(attn) + transpose_w(proj) ----
// (verified R15/R17; -4.7us vs 3 separate launches) blocks 0..1023 convert
// x->bf16; 1024..1455 transpose w_attn; 1456..1599 transpose w_proj.
__global__ __launch_bounds__(256)
void prep_fused(const float* __restrict__ x, unsigned short* __restrict__ xb, int n4,
                const float* __restrict__ wa, unsigned short* __restrict__ wta,
                const float* __restrict__ wp, unsigned short* __restrict__ wtp) {
  __shared__ short tile[64 * 68];
  const int bid = blockIdx.x;
  const int tid = threadIdx.x;
  if (bid < 1024) {
    int i = bid * 256 + tid;
    const int stride = 1024 * 256;
    for (; i < n4; i += stride) {
      float4 v = ((const float4*)x)[i];
      shortx4 s;
      s.x = (short)f2bf(v.x); s.y = (short)f2bf(v.y);
      s.z = (short)f2bf(v.z); s.w = (short)f2bf(v.w);
      ((shortx4*)xb)[i] = s;
    }
    return;
  }
  const float* w; unsigned short* wt; int N, n0, k0;
  if (bid < 1456) {
    const int t = bid - 1024;            // 0..431 : w_attn [768][2304]
    w = wa; wt = wta; N = QKVW; n0 = (t % 36) * 64; k0 = (t / 36) * 64;
  } else {
    const int t = bid - 1456;            // 0..143 : w_proj [768][768]
    w = wp; wt = wtp; N = CC;   n0 = (t % 12) * 64; k0 = (t / 12) * 64;
  }
  const int K = CC;
  {
    const int tr = tid >> 4, tc = (tid & 15) * 4;
#pragma unroll
    for (int i = 0; i < 4; ++i) {
      float4 v = *(const float4*)(w + (size_t)(k0 + tr + 16 * i) * N + n0 + tc);
      short* d = &tile[(tr + 16 * i) * 68 + tc];
      d[0] = (short)f2bf(v.x); d[1] = (short)f2bf(v.y);
      d[2] = (short)f2bf(v.z); d[3] = (short)f2bf(v.w);
    }
  }
  __syncthreads();
  {
    const int wr = tid >> 3, wc = (tid & 7) * 8;
#pragma unroll
    for (int j = 0; j < 2; ++j) {
      const int n = wr + 32 * j;
      shortx8 s;
#pragma unroll
      for (int e = 0; e < 8; ++e) s[e] = tile[(wc + e) * 68 + n];
      *(shortx8*)(wt + (size_t)(n0 + n) * K + k0 + wc) = s;
    }
  }
}

// V part of qkv -> Vt[bh][d][t] bf16, keyPerm within 32-blocks. VERIFIED R8/R9.
__global__ __launch_bounds__(256)
void transpose_v(const unsigned short* __restrict__ qkv, unsigned short* __restrict__ Vt) {
  __shared__ short tile[64 * 72];   // [t'][d]
  const int t0 = blockIdx.x * 64;
  const int bh = blockIdx.y;
  const int b = bh / NHH, h = bh % NHH;
  const int tid = threadIdx.x;
  {
    const int tr = tid >> 3, tc = (tid & 7) * 8;
#pragma unroll
    for (int i = 0; i < 2; ++i) {
      shortx8 v = *(const shortx8*)(qkv + ((size_t)(b * TT + t0 + tr + 32 * i)) * QKVW + 2 * CC + h * HSS + tc);
      *(shortx8*)&tile[(tr + 32 * i) * 72 + tc] = v;
    }
  }
  __syncthreads();
  {
    const int dr = tid >> 3, tc = (tid & 7) * 8;
    const int base = (tc & 32) + ((tc >> 3) & 3) * 4;   // 32-block + q*4
#pragma unroll
    for (int j = 0; j < 2; ++j) {
      const int d = dr + 32 * j;
      shortx8 s;
#pragma unroll
      for (int e = 0; e < 8; ++e)
        s[e] = tile[(base + (e >> 2) * 16 + (e & 3)) * 72 + d];
      *(shortx8*)(Vt + ((size_t)bh * HSS + d) * TT + t0 + tc) = s;
    }
  }
}

// ---------- GEMM v5: 2-buffer pipelined BK=32, counted vmcnt(4) ------------
// R18: all MFMA kernels were latency-bound (MfmaUtil~22, Occ~22, LDS pipe
// far from saturated). The 3rd buffer cost residency: 48KB -> 3 blocks/CU
// and grid 1152 = 1.5 fills (tail round half-empty). 2-buffer (32KB) -> 5
// blocks/CU (20 waves), grid fits ~one fill. Depth-1 prefetch cover (~1
// iter) suffices for the mostly-L2-hit panel loads; the +8 waves/CU of TLP
// covers the rest. Same verified skeleton: counted vmcnt (4 steady / 0
// tail), raw s_barrier pair, sched_barrier(0) fences (rule #18), both-sides
// chunk-XOR swizzle (rule #21). R16's occupancy-floor rule respected (>=3
// resident blocks/CU; now 5).
template<bool OUT_BF16, bool QSCALE>
__global__ __launch_bounds__(256)
void gemm_tn(const unsigned short* __restrict__ A, const unsigned short* __restrict__ Bt,
             const float* __restrict__ bias, void* __restrict__ Cp, int M, int N, int K) {
  __shared__ short As[2][128 * 32];
  __shared__ short Bs[2][128 * 32];
  const int tid = threadIdx.x, lane = tid & 63, wave = tid >> 6;
  const int row = lane & 15, quad = lane >> 4;
  const int wm = (wave >> 1) * 64, wn = (wave & 1) * 64;
  const int m0 = blockIdx.x * 128, n0 = blockIdx.y * 128;

  floatx4 acc[4][4] = {};

  const int lr = lane >> 2;                       // local row in 16-row granule
  const int csrc = (lane & 3) ^ ((lr >> 1) & 3);  // swizzled source chunk
  const int sr = wave * 32 + lr;
  const unsigned short* aP = A + (size_t)(m0 + sr) * K + csrc * 8;
  const unsigned short* bP = Bt + (size_t)(n0 + sr) * K + csrc * 8;
  const int sOff = (wave * 32) * 32;              // this wave's LDS base (shorts)

  const int qsw = (quad ^ ((row >> 1) & 3)) * 8;

  const int nk = K >> 5;                          // BK=32 steps (24 for K=768)

  auto stage = [&](int t, int bi) {
#pragma unroll
    for (int i = 0; i < 2; ++i) {
      async_copy16(aP + (size_t)(16 * i) * K + t * 32, &As[bi][sOff + i * 512]);
      async_copy16(bP + (size_t)(16 * i) * K + t * 32, &Bs[bi][sOff + i * 512]);
    }
  };

  stage(0, 0);
  int cb = 0;
  for (int t = 0; t < nk; ++t) {
    if (t + 1 < nk) {
      stage(t + 1, cb ^ 1);
      asm volatile("s_waitcnt vmcnt(4)" ::: "memory");   // tile t landed
    } else {
      asm volatile("s_waitcnt vmcnt(0)" ::: "memory");
    }
    __builtin_amdgcn_sched_barrier(0);
    __builtin_amdgcn_s_barrier();
    __builtin_amdgcn_sched_barrier(0);
    {
      shortx8 af[4], bf[4];
#pragma unroll
      for (int g = 0; g < 4; ++g) {
        af[g] = *(const shortx8*)&As[cb][(wm + g * 16 + row) * 32 + qsw];
        bf[g] = *(const shortx8*)&Bs[cb][(wn + g * 16 + row) * 32 + qsw];
      }
#pragma unroll
      for (int mg = 0; mg < 4; ++mg)
#pragma unroll
        for (int ng = 0; ng < 4; ++ng)
          acc[mg][ng] = __builtin_amdgcn_mfma_f32_16x16x32_bf16(af[mg], bf[ng], acc[mg][ng], 0, 0, 0);
    }
    __builtin_amdgcn_sched_barrier(0);
    __builtin_amdgcn_s_barrier();
    __builtin_amdgcn_sched_barrier(0);
    cb ^= 1;
  }

#pragma unroll
  for (int mg = 0; mg < 4; ++mg) {
    const int m = m0 + wm + mg * 16 + quad * 4;
#pragma unroll
    for (int ng = 0; ng < 4; ++ng) {
      const int n = n0 + wn + ng * 16 + row;
      const float bv = bias[n];
      // fold attn 1/sqrt(HS) AND log2(e) into q (softmax uses exp2)
      const float scl = (QSCALE && n < CC) ? 0.180336881f : 1.0f;
#pragma unroll
      for (int r = 0; r < 4; ++r) {
        const float val = (acc[mg][ng][r] + bv) * scl;
        if (OUT_BF16) ((unsigned short*)Cp)[(size_t)(m + r) * N + n] = f2bf(val);
        else          ((float*)Cp)[(size_t)(m + r) * N + n] = val;
      }
    }
  }
}

// ---------- flash attention v13: 2-buffer DMA, 5 blocks/CU -----------------
// R18: v12's 3rd buffer (48KB) silently cut residency to 3 blocks/CU.
// 2-buffer combined sh[buf][K/V] = 32KB -> 5 blocks/CU (20 waves). Counted
// vmcnt(4) steady / vmcnt(0) tail; with XCD-pinned K/V streams the loads are
// L2-hit-class, so 1 iteration of cover suffices. Data path, offsets,
// swizzle, grid (1536 LPT XCD-pinned) identical to verified v12. Reduction
// overlay (22.5KB) fits the combined 32KB buffer after the final barrier.
__global__ __launch_bounds__(256)
void attn_kernel(const unsigned short* __restrict__ qkv, const unsigned short* __restrict__ Vt,
                 unsigned short* __restrict__ y) {
  __shared__ short sh[2][2][64 * 64];   // [buf][0=K(key,d) 1=V(d,keyPerm)], swizzled

  // XCD-locality + LPT decode (assumes round-robin blockIdx%8 -> XCD)
  const int id = blockIdx.x;          // 0..1535
  const int xcd = id & 7;
  const int slot = id >> 3;           // 0..191
  const int qt = NQT64 - 1 - slot / 6;   // 31..0, heavy first
  const int gl = slot % 6;
  const int g = xcd * 6 + gl;         // 0..47 = (b,h) group
  const int h = g % NHH, b = g / NHH;
  const int bh = b * NHH + h;
  const int tid = threadIdx.x, lane = tid & 63, wave = tid >> 6;
  const int row = lane & 15, quad = lane >> 4;
  const int qhalf = wave & 1;         // which 32 queries of the 64-q item
  const int khalf = wave >> 1;        // which 32 keys of each 64-key tile

  const unsigned short* kSrc = qkv + ((size_t)(b * TT)) * QKVW + CC + h * HSS;
  const unsigned short* vSrc = Vt + ((size_t)bh * HSS) * TT;

  const shortx8 ones8 = {(short)0x3F80, (short)0x3F80, (short)0x3F80, (short)0x3F80,
                         (short)0x3F80, (short)0x3F80, (short)0x3F80, (short)0x3F80};

  const int qb0 = qt * 64 + qhalf * 32;             // wave's 32 queries
  const int nk = qt + 1;

  // ---- staging source per-lane offsets (inverse-swizzled chunk) ----
  const int lr8 = lane >> 3;          // 0..7 (== staged row & 7)
  const int csw = ((lane & 7) ^ lr8) * 8;
  size_t kOff[2], vOff[2];
#pragma unroll
  for (int i = 0; i < 2; ++i) {
    const int r = wave * 16 + i * 8 + lr8;
    kOff[i] = (size_t)r * QKVW + csw;
    vOff[i] = (size_t)r * TT + csw;
  }
  const int sBase = (wave * 16) * 64; // this wave's LDS base (shorts), +i*512

  // ---- read offsets (loop-invariant, chunk-XOR by row&7) ----
  const int r7 = row & 7;
  int kR[2][2], vR[4];
#pragma unroll
  for (int mg = 0; mg < 2; ++mg) {
    const int krow = khalf * 32 + mg * 16 + row;
    kR[mg][0] = krow * 64 + ((quad ^ r7) * 8);
    kR[mg][1] = krow * 64 + (((quad + 4) ^ r7) * 8);
  }
#pragma unroll
  for (int dg = 0; dg < 4; ++dg)
    vR[dg] = (dg * 16 + row) * 64 + (((khalf * 4 + quad) ^ r7) * 8);

  // Q fragments (B-operand of S^T MFMA); pre-scaled by 0.125*log2e in GEMM1
  shortx8 qf[2][2];
#pragma unroll
  for (int qg = 0; qg < 2; ++qg) {
    const unsigned short* qp = qkv + ((size_t)(b * TT) + qb0 + qg * 16 + row) * QKVW + h * HSS;
    qf[qg][0] = *(const shortx8*)(qp + quad * 8);
    qf[qg][1] = *(const shortx8*)(qp + 32 + quad * 8);
  }
  asm volatile("s_waitcnt vmcnt(0)" ::: "memory");   // Q done -> exact DMA counting

  floatx4 lf[2] = {(floatx4)(0.0f), (floatx4)(0.0f)};  // partial l (this khalf)
  floatx4 o[2][4];                  // [qg][dg]: O[q=quad*4+r][d=dg*16+row] partial
#pragma unroll
  for (int qg = 0; qg < 2; ++qg)
#pragma unroll
    for (int dg = 0; dg < 4; ++dg) o[qg][dg] = (floatx4)(0.0f);

  auto stage = [&](int t, int bi) {
#pragma unroll
    for (int i = 0; i < 2; ++i) {
      async_copy16(kSrc + (size_t)(t * 64) * QKVW + kOff[i], &sh[bi][0][sBase + i * 512]);
      async_copy16(vSrc + (size_t)(t * 64) + vOff[i],        &sh[bi][1][sBase + i * 512]);
    }
  };

  stage(0, 0);
  int cb = 0;
  for (int kt = 0; kt < nk; ++kt) {
    if (kt + 1 < nk) {
      stage(kt + 1, cb ^ 1);
      asm volatile("s_waitcnt vmcnt(4)" ::: "memory");   // tile kt landed
    } else {
      asm volatile("s_waitcnt vmcnt(0)" ::: "memory");
    }
    __builtin_amdgcn_sched_barrier(0);
    __builtin_amdgcn_s_barrier();
    __builtin_amdgcn_sched_barrier(0);
    {
      const short* Kc = &sh[cb][0][0];
      const short* Vc = &sh[cb][1][0];
      __builtin_amdgcn_s_setprio(1);
      // ---- S^T = K @ Q^T (this wave: 32 keys x 32 queries) ----
      // lane holds S[key = khalf*32+mg*16+quad*4+r][q = qg*16+row]
      shortx4 pfr[2][2];
#pragma unroll
      for (int mg = 0; mg < 2; ++mg) {
        const shortx8 kf0 = *(const shortx8*)&Kc[kR[mg][0]];
        const shortx8 kf1 = *(const shortx8*)&Kc[kR[mg][1]];
#pragma unroll
        for (int qg = 0; qg < 2; ++qg) {
          floatx4 t = __builtin_amdgcn_mfma_f32_16x16x32_bf16(kf0, qf[qg][0], (floatx4)(0.0f), 0, 0, 0);
          t = __builtin_amdgcn_mfma_f32_16x16x32_bf16(kf1, qf[qg][1], t, 0, 0, 0);
          if (kt == qt) {  // diagonal tile: causal mask (key > query)
            const int kg = kt * 64 + khalf * 32 + mg * 16 + quad * 4;
            const int qv = qb0 + qg * 16 + row;
#pragma unroll
            for (int r = 0; r < 4; ++r)
              if (kg + r > qv) t[r] = -1e30f;
          }
          // softmax numerator: p = exp2(s), fixed max, truncation pack
          shortx4 pk;
#pragma unroll
          for (int r = 0; r < 4; ++r) pk[r] = (short)bft(__builtin_amdgcn_exp2f(t[r]));
          pfr[qg][mg] = pk;
        }
      }
      // ---- O += P @ V ; l += P @ 1 — k=32 MFMA over this wave's 32 keys ----
      shortx8 pk8[2];
#pragma unroll
      for (int qg = 0; qg < 2; ++qg) {
        pk8[qg] = __builtin_shufflevector(pfr[qg][0], pfr[qg][1], 0, 1, 2, 3, 4, 5, 6, 7);
        lf[qg] = __builtin_amdgcn_mfma_f32_16x16x32_bf16(pk8[qg], ones8, lf[qg], 0, 0, 0);
      }
#pragma unroll
      for (int dg = 0; dg < 4; ++dg) {
        const shortx8 vf = *(const shortx8*)&Vc[vR[dg]];
#pragma unroll
        for (int qg = 0; qg < 2; ++qg)
          o[qg][dg] = __builtin_amdgcn_mfma_f32_16x16x32_bf16(pk8[qg], vf, o[qg][dg], 0, 0, 0);
      }
      __builtin_amdgcn_s_setprio(0);
    }
    __builtin_amdgcn_sched_barrier(0);
    __builtin_amdgcn_s_barrier();
    __builtin_amdgcn_sched_barrier(0);
    cb ^= 1;
  }

  // ---- cross-khalf reduction of O,l through the (dead) staging LDS ----
  // stride 11 floatx4 per lane: granule = 3*lane+slot mod 8 -> conflict-free.
  floatx4* red4 = (floatx4*)(&sh[0][0][0]);   // 2*64*11*16B = 22.5KB <= 32KB
  const int rbase = (qhalf * 64 + lane) * 11;
  if (khalf) {
#pragma unroll
    for (int qg = 0; qg < 2; ++qg) {
#pragma unroll
      for (int dg = 0; dg < 4; ++dg) red4[rbase + qg * 4 + dg] = o[qg][dg];
      red4[rbase + 8 + qg] = lf[qg];
    }
  }
  __syncthreads();
  if (!khalf) {
#pragma unroll
    for (int qg = 0; qg < 2; ++qg) {
#pragma unroll
      for (int dg = 0; dg < 4; ++dg) o[qg][dg] += red4[rbase + qg * 4 + dg];
      lf[qg] += red4[rbase + 8 + qg];
    }
    // epilogue: l is per-lane in C-layout -> no shuffles at all
#pragma unroll
    for (int qg = 0; qg < 2; ++qg) {
#pragma unroll
      for (int r = 0; r < 4; ++r) {
        const float lo = 1.0f / lf[qg][r];
        unsigned short* yp = y + ((size_t)(b * TT) + qb0 + qg * 16 + quad * 4 + r) * CC + h * HSS;
#pragma unroll
        for (int dg = 0; dg < 4; ++dg)
          yp[dg * 16 + row] = bfp(o[qg][dg][r] * lo);
      }
    }
  }
}

extern "C" void kernel_launch(void* const* d_in, const int* in_sizes, int n_in,
                              void* d_out, int out_size, void* d_ws, size_t ws_size,
                              hipStream_t stream) {
  const float* x      = (const float*)d_in[0];
  const float* w_attn = (const float*)d_in[1];
  const float* b_attn = (const float*)d_in[2];
  const float* w_proj = (const float*)d_in[3];
  const float* b_proj = (const float*)d_in[4];
  float* out = (float*)d_out;

  char* ws = (char*)d_ws;
  unsigned short* xb  = (unsigned short*)ws;
  unsigned short* y   = (unsigned short*)ws;                          // reuse after GEMM1
  unsigned short* qkv = (unsigned short*)(ws + 12582912);
  unsigned short* wta = (unsigned short*)(ws + 50331648);
  unsigned short* Vt  = (unsigned short*)(ws + 50331648);             // overlays wta post-GEMM1
  unsigned short* wtp = (unsigned short*)(ws + 62914560);

  const int M = BB * TT;  // 8192

  prep_fused<<<1600, 256, 0, stream>>>(x, xb, (M * CC) / 4, w_attn, wta, w_proj, wtp);

  gemm_tn<true, true><<<dim3(M / 128, QKVW / 128), 256, 0, stream>>>(
      xb, wta, b_attn, (void*)qkv, M, QKVW, CC);

  transpose_v<<<dim3(TT / 64, BB * NHH), 256, 0, stream>>>(qkv, Vt);

  attn_kernel<<<dim3(NQT64 * NHH * BB), 256, 0, stream>>>(qkv, Vt, y);

  gemm_tn<false, false><<<dim3(M / 128, CC / 128), 256, 0, stream>>>(
      y, wtp, b_proj, (void*)out, M, CC, CC);
}